// Round 1
// baseline (134.680 us; speedup 1.0000x reference)
//
#include <hip/hip_runtime.h>
#include <hip/hip_bf16.h>

#define BSZ 4096
#define DIM 512
#define NCLS 64
#define MARGIN_F 1.0f

typedef short short8 __attribute__((ext_vector_type(8)));
typedef float floatx4 __attribute__((ext_vector_type(4)));
typedef unsigned short u16;

// ---------------- workspace layout ----------------
// [0)              : ebf16  BSZ*DIM u16   (4 MiB) normalized bf16 embeddings
// [4194304)        : pos_sum BSZ float
// [4210688)        : neg_min BSZ uint (float bits, dist>=0 so monotonic)
// [4227072)        : hist   NCLS int
#define OFF_POS  4194304
#define OFF_NEG  (OFF_POS + BSZ * 4)
#define OFF_HIST (OFF_NEG + BSZ * 4)

__global__ void ht_init(float* pos_sum, unsigned* neg_min, int* hist) {
    int i = blockIdx.x * blockDim.x + threadIdx.x;
    if (i < BSZ) { pos_sum[i] = 0.0f; neg_min[i] = 0x7F800000u; }
    if (i < NCLS) hist[i] = 0;
}

__device__ __forceinline__ u16 f2bf_rne(float f) {
    unsigned x = __float_as_uint(f);
    x += 0x7FFFu + ((x >> 16) & 1u);
    return (u16)(x >> 16);
}

// one wave per row: L2 normalize, cast bf16, build class histogram
__global__ void ht_normalize(const float* __restrict__ emb,
                             const int* __restrict__ labels,
                             u16* __restrict__ ebf, int* __restrict__ hist) {
    const int row = blockIdx.x;
    const int t = threadIdx.x;          // 0..63, 8 elems each
    const float4* r4 = (const float4*)(emb + row * DIM);
    float4 v0 = r4[t * 2];
    float4 v1 = r4[t * 2 + 1];
    float s = v0.x * v0.x + v0.y * v0.y + v0.z * v0.z + v0.w * v0.w
            + v1.x * v1.x + v1.y * v1.y + v1.z * v1.z + v1.w * v1.w;
#pragma unroll
    for (int off = 1; off < 64; off <<= 1) s += __shfl_xor(s, off);
    const float inv = 1.0f / fmaxf(sqrtf(s), 1e-12f);

    uint4 o;
    o.x = (unsigned)f2bf_rne(v0.x * inv) | ((unsigned)f2bf_rne(v0.y * inv) << 16);
    o.y = (unsigned)f2bf_rne(v0.z * inv) | ((unsigned)f2bf_rne(v0.w * inv) << 16);
    o.z = (unsigned)f2bf_rne(v1.x * inv) | ((unsigned)f2bf_rne(v1.y * inv) << 16);
    o.w = (unsigned)f2bf_rne(v1.z * inv) | ((unsigned)f2bf_rne(v1.w * inv) << 16);
    ((uint4*)(ebf + row * DIM))[t] = o;

    if (t == 0) atomicAdd(&hist[labels[row]], 1);
}

// 128x128 output tile per block; 4 waves in 2x2; each wave 64x64 via 4x4
// mfma_f32_16x16x32_bf16 accs. Fused epilogue: dist -> per-row pos-sum /
// neg-min partials -> quad shuffle-reduce -> global atomics.
__global__ __launch_bounds__(256) void ht_gemm_reduce(
        const u16* __restrict__ ebf, const int* __restrict__ labels,
        float* __restrict__ pos_sum, unsigned* __restrict__ neg_min) {
    __shared__ u16 sA[128 * 32];
    __shared__ u16 sB[128 * 32];
    __shared__ int sLI[128];
    __shared__ int sLJ[128];

    const int t = threadIdx.x;
    const int row0 = blockIdx.y * 128;
    const int col0 = blockIdx.x * 128;

    if (t < 128) sLI[t] = labels[row0 + t];
    else         sLJ[t - 128] = labels[col0 + t - 128];

    const int lane = t & 63;
    const int wave = t >> 6;
    const int wr = (wave >> 1) * 64;    // wave row offset in tile
    const int wc = (wave & 1) * 64;     // wave col offset in tile
    const int l15 = lane & 15;
    const int quad = lane >> 4;

    // staging map: chunk c in {0,1}: linear = c*256+t -> row linear/4,
    // 16B segment linear%4 (8 bf16). LDS row-major 128x32, unpadded.
    const int lin0 = t, lin1 = 256 + t;
    const int ar0 = lin0 >> 2, ac0 = (lin0 & 3) * 8;
    const int ar1 = lin1 >> 2, ac1 = (lin1 & 3) * 8;

    floatx4 acc[4][4] = {};

    for (int kk = 0; kk < DIM; kk += 32) {
        uint4 a0 = *(const uint4*)(ebf + (row0 + ar0) * DIM + kk + ac0);
        uint4 a1 = *(const uint4*)(ebf + (row0 + ar1) * DIM + kk + ac1);
        uint4 b0 = *(const uint4*)(ebf + (col0 + ar0) * DIM + kk + ac0);
        uint4 b1 = *(const uint4*)(ebf + (col0 + ar1) * DIM + kk + ac1);
        __syncthreads();
        ((uint4*)sA)[lin0] = a0;
        ((uint4*)sA)[lin1] = a1;
        ((uint4*)sB)[lin0] = b0;
        ((uint4*)sB)[lin1] = b1;
        __syncthreads();

        short8 af[4], bf[4];
#pragma unroll
        for (int mi = 0; mi < 4; ++mi)
            af[mi] = *(const short8*)(sA + (wr + mi * 16 + l15) * 32 + quad * 8);
#pragma unroll
        for (int ni = 0; ni < 4; ++ni)
            bf[ni] = *(const short8*)(sB + (wc + ni * 16 + l15) * 32 + quad * 8);
#pragma unroll
        for (int mi = 0; mi < 4; ++mi)
#pragma unroll
            for (int ni = 0; ni < 4; ++ni)
                acc[mi][ni] = __builtin_amdgcn_mfma_f32_16x16x32_bf16(
                    af[mi], bf[ni], acc[mi][ni], 0, 0, 0);
    }

    // epilogue: C/D layout col=l15, row=quad*4+reg (verified m89/m91)
    const float INF = __uint_as_float(0x7F800000u);
#pragma unroll
    for (int mi = 0; mi < 4; ++mi) {
        const int rbase = wr + mi * 16 + quad * 4;
#pragma unroll
        for (int r = 0; r < 4; ++r) {
            const int rloc = rbase + r;
            const int gi = row0 + rloc;
            const int rl = sLI[rloc];
            float ps = 0.0f;
            float nm = INF;
#pragma unroll
            for (int ni = 0; ni < 4; ++ni) {
                const int cloc = wc + ni * 16 + l15;
                const int cl = sLJ[cloc];
                const float dot = acc[mi][ni][r];
                const float d = sqrtf(fmaxf(2.0f - 2.0f * dot, 0.0f));
                if (rl == cl) {
                    if (gi != (col0 + cloc)) ps += d;
                } else {
                    nm = fminf(nm, d);
                }
            }
#pragma unroll
            for (int off = 1; off < 16; off <<= 1) {
                ps += __shfl_xor(ps, off);
                nm = fminf(nm, __shfl_xor(nm, off));
            }
            if (l15 == 0) {
                if (ps != 0.0f) atomicAdd(&pos_sum[gi], ps);
                atomicMin(&neg_min[gi], __float_as_uint(nm));
            }
        }
    }
}

__global__ void ht_finalize(const float* __restrict__ pos_sum,
                            const unsigned* __restrict__ neg_min,
                            const int* __restrict__ labels,
                            const int* __restrict__ hist,
                            float* __restrict__ out) {
    __shared__ float sT[4];
    __shared__ int sN[4];
    const int t = threadIdx.x;
    float total = 0.0f;
    int nv = 0;
    for (int i = t; i < BSZ; i += 256) {
        const int cnt = hist[labels[i]];
        const int pc = cnt - 1;
        const int nc = BSZ - cnt;
        if (pc > 0 && nc > 0) {
            const float psr = pos_sum[i] / (float)pc;
            const float ns = __uint_as_float(neg_min[i]);
            total += fmaxf(psr - ns + MARGIN_F, 0.0f);
            nv += 1;
        }
    }
#pragma unroll
    for (int off = 1; off < 64; off <<= 1) {
        total += __shfl_xor(total, off);
        nv += __shfl_xor(nv, off);
    }
    if ((t & 63) == 0) { sT[t >> 6] = total; sN[t >> 6] = nv; }
    __syncthreads();
    if (t == 0) {
        const float tt = sT[0] + sT[1] + sT[2] + sT[3];
        const int nn = sN[0] + sN[1] + sN[2] + sN[3];
        out[0] = (nn > 0) ? tt / (float)nn : 0.0f;
    }
}

extern "C" void kernel_launch(void* const* d_in, const int* in_sizes, int n_in,
                              void* d_out, int out_size, void* d_ws, size_t ws_size,
                              hipStream_t stream) {
    const float* emb = (const float*)d_in[0];
    const int* labels = (const int*)d_in[1];
    float* out = (float*)d_out;
    char* ws = (char*)d_ws;

    u16* ebf = (u16*)ws;
    float* pos_sum = (float*)(ws + OFF_POS);
    unsigned* neg_min = (unsigned*)(ws + OFF_NEG);
    int* hist = (int*)(ws + OFF_HIST);

    ht_init<<<(BSZ + 255) / 256, 256, 0, stream>>>(pos_sum, neg_min, hist);
    ht_normalize<<<BSZ, 64, 0, stream>>>(emb, labels, ebf, hist);
    dim3 g(BSZ / 128, BSZ / 128);
    ht_gemm_reduce<<<g, 256, 0, stream>>>(ebf, labels, pos_sum, neg_min);
    ht_finalize<<<1, 256, 0, stream>>>(pos_sum, neg_min, labels, hist, out);
}

// Round 2
// 111.635 us; speedup vs baseline: 1.2064x; 1.2064x over previous
//
#include <hip/hip_runtime.h>
#include <hip/hip_bf16.h>

#define BSZ 4096
#define DIM 512
#define NCLS 64
#define MARGIN_F 1.0f
#define NT 32                    // 4096/128 tiles per dim
#define NBLK (NT * (NT + 1) / 2) // 528 upper-tri tiles

typedef short short8 __attribute__((ext_vector_type(8)));
typedef float floatx4 __attribute__((ext_vector_type(4)));
typedef unsigned short u16;

// ---------------- workspace layout ----------------
// [0)       : ebf16  BSZ*DIM u16 (4 MiB) normalized bf16 embeddings
// [OFF_POS) : pos_sum BSZ float
// [OFF_NEG) : neg_min BSZ uint (float bits; dist>=0 so bit-order == value-order)
#define OFF_POS  (BSZ * DIM * 2)
#define OFF_NEG  (OFF_POS + BSZ * 4)

__device__ __forceinline__ u16 f2bf_rne(float f) {
    unsigned x = __float_as_uint(f);
    x += 0x7FFFu + ((x >> 16) & 1u);
    return (u16)(x >> 16);
}

// async global->LDS, 16 B per lane; LDS dest is wave-uniform base + lane*16
__device__ __forceinline__ void gld_lds16(const u16* g, u16* l) {
    __builtin_amdgcn_global_load_lds(
        (const __attribute__((address_space(1))) unsigned int*)g,
        (__attribute__((address_space(3))) unsigned int*)l, 16, 0, 0);
}

// 4 waves/block, one row per wave: L2-normalize, cast bf16, init row accums.
__global__ __launch_bounds__(256) void ht_normalize(
        const float* __restrict__ emb, u16* __restrict__ ebf,
        float* __restrict__ pos_sum, unsigned* __restrict__ neg_min) {
    const int lane = threadIdx.x & 63;
    const int row = blockIdx.x * 4 + (threadIdx.x >> 6);
    const float4* r4 = (const float4*)(emb + (size_t)row * DIM);
    float4 v0 = r4[lane * 2];
    float4 v1 = r4[lane * 2 + 1];
    float s = v0.x * v0.x + v0.y * v0.y + v0.z * v0.z + v0.w * v0.w
            + v1.x * v1.x + v1.y * v1.y + v1.z * v1.z + v1.w * v1.w;
#pragma unroll
    for (int off = 1; off < 64; off <<= 1) s += __shfl_xor(s, off);
    const float inv = 1.0f / fmaxf(sqrtf(s), 1e-12f);

    uint4 o;
    o.x = (unsigned)f2bf_rne(v0.x * inv) | ((unsigned)f2bf_rne(v0.y * inv) << 16);
    o.y = (unsigned)f2bf_rne(v0.z * inv) | ((unsigned)f2bf_rne(v0.w * inv) << 16);
    o.z = (unsigned)f2bf_rne(v1.x * inv) | ((unsigned)f2bf_rne(v1.y * inv) << 16);
    o.w = (unsigned)f2bf_rne(v1.z * inv) | ((unsigned)f2bf_rne(v1.w * inv) << 16);
    ((uint4*)(ebf + (size_t)row * DIM))[lane] = o;

    if (lane == 0) { pos_sum[row] = 0.0f; neg_min[row] = 0x7F800000u; }
}

// Upper-triangular 128x128 tiles. 4 waves in 2x2, each wave 64x64 via 4x4
// mfma_f32_16x16x32_bf16. LDS layout chunk-major: [k-chunk 4][row 128][8 u16]
// -> fragment ds_read_b128 is lane-contiguous (conflict-free) AND matches
// global_load_lds's base+lane*16 fill order.
// Epilogue: row stats always; column stats on off-diagonal tiles (symmetry).
__global__ __launch_bounds__(256) void ht_gemm_reduce(
        const u16* __restrict__ ebf, const int* __restrict__ labels,
        float* __restrict__ pos_sum, unsigned* __restrict__ neg_min) {
    __shared__ u16 sA[4 * 128 * 8];
    __shared__ u16 sB[4 * 128 * 8];
    __shared__ int sLI[128];
    __shared__ int sLJ[128];

    // decode linear block id -> upper-tri (by, bx), by <= bx
    int rem = blockIdx.x, by = 0;
    while (rem >= NT - by) { rem -= NT - by; ++by; }
    const int bx = by + rem;
    const bool offd = (bx != by);

    const int t = threadIdx.x;
    const int row0 = by * 128;
    const int col0 = bx * 128;

    if (t < 128) sLI[t] = labels[row0 + t];
    else         sLJ[t - 128] = labels[col0 + t - 128];

    const int lane = t & 63;
    const int wave = t >> 6;
    const int wr = (wave >> 1) * 64;
    const int wc = (wave & 1) * 64;
    const int l15 = lane & 15;
    const int quad = lane >> 4;

    floatx4 acc[4][4] = {};

    for (int kk = 0; kk < DIM; kk += 32) {
        __syncthreads();   // previous fragments consumed before overwrite
#pragma unroll
        for (int q = 0; q < 2; ++q) {
            const int L = q * 256 + t;          // 16B-segment index, 0..511
            const int row = L & 127;
            const int ch = L >> 7;
            const u16* ga = ebf + (size_t)(row0 + row) * DIM + kk + ch * 8;
            const u16* gb = ebf + (size_t)(col0 + row) * DIM + kk + ch * 8;
            const int lb = (q * 256 + wave * 64) * 8;  // wave-uniform LDS base
            gld_lds16(ga, sA + lb);
            gld_lds16(gb, sB + lb);
        }
        __syncthreads();   // drains vmcnt before barrier (compiler-inserted)

        short8 af[4], bf[4];
#pragma unroll
        for (int mi = 0; mi < 4; ++mi)
            af[mi] = *(const short8*)(sA + (quad * 128 + wr + mi * 16 + l15) * 8);
#pragma unroll
        for (int ni = 0; ni < 4; ++ni)
            bf[ni] = *(const short8*)(sB + (quad * 128 + wc + ni * 16 + l15) * 8);
#pragma unroll
        for (int mi = 0; mi < 4; ++mi)
#pragma unroll
            for (int ni = 0; ni < 4; ++ni)
                acc[mi][ni] = __builtin_amdgcn_mfma_f32_16x16x32_bf16(
                    af[mi], bf[ni], acc[mi][ni], 0, 0, 0);
    }

    // epilogue: C/D layout col=l15, row=quad*4+reg (m89/m91 verified)
    const float INF = __uint_as_float(0x7F800000u);
    float psc[4] = {0.f, 0.f, 0.f, 0.f};
    float nmc[4] = {INF, INF, INF, INF};
#pragma unroll
    for (int mi = 0; mi < 4; ++mi) {
        const int rbase = wr + mi * 16 + quad * 4;
#pragma unroll
        for (int r = 0; r < 4; ++r) {
            const int rloc = rbase + r;
            const int gi = row0 + rloc;
            const int rl = sLI[rloc];
            float ps = 0.0f, nm = INF;
#pragma unroll
            for (int ni = 0; ni < 4; ++ni) {
                const int cloc = wc + ni * 16 + l15;
                const int cl = sLJ[cloc];
                const float d = sqrtf(fmaxf(2.0f - 2.0f * acc[mi][ni][r], 0.0f));
                if (rl == cl) {
                    if (gi != col0 + cloc) ps += d;   // drop self-pair (diag)
                    if (offd) psc[ni] += d;
                } else {
                    nm = fminf(nm, d);
                    if (offd) nmc[ni] = fminf(nmc[ni], d);
                }
            }
#pragma unroll
            for (int off = 1; off < 16; off <<= 1) {
                ps += __shfl_xor(ps, off);
                nm = fminf(nm, __shfl_xor(nm, off));
            }
            if (l15 == 0) {
                if (ps != 0.0f) atomicAdd(&pos_sum[gi], ps);
                atomicMin(&neg_min[gi], __float_as_uint(nm));
            }
        }
    }
    if (offd) {
        // column stats: reduce each lane's 16-row partial across the 4 quads
#pragma unroll
        for (int ni = 0; ni < 4; ++ni) {
            float ps = psc[ni], nm = nmc[ni];
            ps += __shfl_xor(ps, 16); ps += __shfl_xor(ps, 32);
            nm = fminf(nm, __shfl_xor(nm, 16));
            nm = fminf(nm, __shfl_xor(nm, 32));
            if (quad == 0) {
                const int gj = col0 + wc + ni * 16 + l15;
                if (ps != 0.0f) atomicAdd(&pos_sum[gj], ps);
                atomicMin(&neg_min[gj], __float_as_uint(nm));
            }
        }
    }
}

__global__ void ht_finalize(const float* __restrict__ pos_sum,
                            const unsigned* __restrict__ neg_min,
                            const int* __restrict__ labels,
                            float* __restrict__ out) {
    __shared__ int shist[NCLS];
    __shared__ float sT[4];
    __shared__ int sN[4];
    const int t = threadIdx.x;
    if (t < NCLS) shist[t] = 0;
    __syncthreads();
    for (int i = t; i < BSZ; i += 256) atomicAdd(&shist[labels[i]], 1);
    __syncthreads();

    float total = 0.0f;
    int nv = 0;
    for (int i = t; i < BSZ; i += 256) {
        const int cnt = shist[labels[i]];
        const int pc = cnt - 1;
        const int nc = BSZ - cnt;
        if (pc > 0 && nc > 0) {
            const float psr = pos_sum[i] / (float)pc;
            const float ns = __uint_as_float(neg_min[i]);
            total += fmaxf(psr - ns + MARGIN_F, 0.0f);
            nv += 1;
        }
    }
#pragma unroll
    for (int off = 1; off < 64; off <<= 1) {
        total += __shfl_xor(total, off);
        nv += __shfl_xor(nv, off);
    }
    if ((t & 63) == 0) { sT[t >> 6] = total; sN[t >> 6] = nv; }
    __syncthreads();
    if (t == 0) {
        const float tt = sT[0] + sT[1] + sT[2] + sT[3];
        const int nn = sN[0] + sN[1] + sN[2] + sN[3];
        out[0] = (nn > 0) ? tt / (float)nn : 0.0f;
    }
}

extern "C" void kernel_launch(void* const* d_in, const int* in_sizes, int n_in,
                              void* d_out, int out_size, void* d_ws, size_t ws_size,
                              hipStream_t stream) {
    const float* emb = (const float*)d_in[0];
    const int* labels = (const int*)d_in[1];
    float* out = (float*)d_out;
    char* ws = (char*)d_ws;

    u16* ebf = (u16*)ws;
    float* pos_sum = (float*)(ws + OFF_POS);
    unsigned* neg_min = (unsigned*)(ws + OFF_NEG);

    ht_normalize<<<BSZ / 4, 256, 0, stream>>>(emb, ebf, pos_sum, neg_min);
    ht_gemm_reduce<<<NBLK, 256, 0, stream>>>(ebf, labels, pos_sum, neg_min);
    ht_finalize<<<1, 256, 0, stream>>>(pos_sum, neg_min, labels, out);
}